// Round 2
// baseline (326.591 us; speedup 1.0000x reference)
//
#include <hip/hip_runtime.h>
#include <hip/hip_fp16.h>

#define NG 16     // num_graphs (fixed by problem)
#define D 64      // feature width at every aggregation point
#define SLOT 32   // CSR slots/node; max in-degree ~Poisson(8.5), P(>=32)~1e-11
#define NPB 128   // nodes per block (512 threads, 8 waves = 8 node-tiles of 16)
#define INH 72    // s_h row stride in halfs (64 + 8 pad: 8B-aligned, bank-balanced)
#define NBANK 16  // stat accumulator banks (cuts same-address atomic pressure)

// fp16 feature rows: 64 halfs = 128 B = 8 float4s. 8 lanes/node, 16 B/lane.
// Tables have N+1 rows; row N is all-zero (gather pad target).
// col[] is memset to 0x7F7F7F7F each launch: pad slots clamp (min) to row N,
// so the gather needs NO deg-dependent index selects at all.
union HF4 { float4 f4; __half2 h2[4]; };
union HF2 { float2 f2; __half2 h2[2]; };

typedef _Float16 half4_t __attribute__((ext_vector_type(4)));
typedef float float4_t __attribute__((ext_vector_type(4)));

__device__ __forceinline__ float2 f2fma(float2 a, float2 b, float2 c) {
  return make_float2(fmaf(a.x, b.x, c.x), fmaf(a.y, b.y, c.y));
}
__device__ __forceinline__ float2 f2add(float2 a, float2 b) {
  return make_float2(a.x + b.x, a.y + b.y);
}

// Issue 16 min-clamped feature gathers (pad -> zero row N).
__device__ __forceinline__ void load16(const float4* __restrict__ feat4, int N,
                                       int q8, int4 a, int4 b, int4 c, int4 d,
                                       HF4* u) {
  int ix[16] = {a.x, a.y, a.z, a.w, b.x, b.y, b.z, b.w,
                c.x, c.y, c.z, c.w, d.x, d.y, d.z, d.w};
#pragma unroll
  for (int i = 0; i < 16; i++)
    u[i].f4 = feat4[(size_t)min(ix[i], N) * 8 + q8];
}
__device__ __forceinline__ void acc16(const HF4* u, float2* acc) {
#pragma unroll
  for (int i = 0; i < 16; i++) {
#pragma unroll
    for (int c = 0; c < 4; c++)
      acc[c] = f2add(acc[c], __half22float2(u[i].h2[c]));
  }
}

// ---------------------------------------------------------------------------
// Fused prep: x->fp16 convert (t < n4) + CSR build (t < E) + pad-row zeroing.
// ---------------------------------------------------------------------------
__global__ void prep_kernel(const float* __restrict__ x,
                            float2* __restrict__ xh, int n4,
                            float4* __restrict__ xz, float4* __restrict__ hz,
                            const int* __restrict__ ei,
                            int* __restrict__ fill, int* __restrict__ col,
                            int E, int per, int tmul) {
  int t = blockIdx.x * 256 + threadIdx.x;
  if (blockIdx.x == 0 && threadIdx.x < 16) {
    float4 z = make_float4(0.f, 0.f, 0.f, 0.f);
    if (threadIdx.x < 8) xz[threadIdx.x] = z;
    else hz[threadIdx.x - 8] = z;
  }
  if (t < n4) {
    float4 v = ((const float4*)x)[t];
    HF2 u;
    u.h2[0] = __floats2half2_rn(v.x, v.y);
    u.h2[1] = __floats2half2_rn(v.z, v.w);
    xh[t] = u.f2;
  }
  if (t < E) {
    int src = ei[t];
    int dst = ei[E + t];
    int thr = (t / per) * tmul;       // compiler magic-div
    if (src >= thr && dst >= thr) {
      int k = atomicAdd(&fill[dst], 1);
      if (k < SLOT) col[dst * SLOT + k] = src;
    }
  }
}

// ---------------------------------------------------------------------------
// Fused layer: wave-autonomous gather + MFMA MLP + per-wave atomic epilogue.
//
// Schedule (one __syncthreads total, right after weight staging):
//   t0: issue col/deg/self + ALL pass-0 gathers  (latency hides under staging)
//   t1: cooperative weight staging -> LDS (fragment order), barrier
//   t2: accumulate pass-0, ds_write; pass-1 gathers (indices prefetched at t0),
//       accumulate, ds_write   [all wave-local rows w*16..w*16+15]
//   t3: s_waitcnt lgkmcnt(0) (wave-local!), MFMA stage1+stage2 in registers
//   t4: per-wave shfl_xor reduce + fire-and-forget atomics into NBANK-banked
//       stat buffers (no LDS tree, no trailing barrier, no convoy)
// Phase B operand identities unchanged: stage1 C/D frag == stage2 B frag.
// ---------------------------------------------------------------------------
template <int MID, bool FOLD_BN, int EPI>
__global__ __launch_bounds__(512, 2) void fused_layer_kernel(
    const float4* __restrict__ feat4,   // fp16 table, 8 float4/row, N+1 rows
    const int* __restrict__ col, const int* __restrict__ deg,
    const float* __restrict__ bn_sum, const float* __restrict__ bn_sq,
    const float* __restrict__ bn_gamma, const float* __restrict__ bn_beta,
    float invN,
    const float* __restrict__ Wa, const float* __restrict__ ba,
    const float* __restrict__ Wb, const float* __restrict__ bb,
    float2* __restrict__ out2,          // EPI==1 only (fp16 rows)
    const int* __restrict__ batch,      // EPI==2 only
    float* __restrict__ st_sum,         // EPI==1: sum[NBANK*64]; EPI==2: pool[NG*64]
    float* __restrict__ st_sq,          // sumsq[NBANK*64]
    float* __restrict__ cnt,            // EPI==2 only
    int N) {
  constexpr int CT = MID / 16;          // stage-1 c-tiles == stage-2 k-tiles

  __shared__ __align__(16) __half s_h[NPB * INH];
  __shared__ __align__(16) __half s_wa[MID * 64];     // Wa^T fragment order
  __shared__ __align__(16) __half s_wb[64 * MID];     // Wb^T fragment order
  __shared__ __align__(16) float s_ba[MID];
  __shared__ __align__(16) float s_bb[D];
  __shared__ float s_bna[FOLD_BN ? D : 1];
  __shared__ float s_bnb[FOLD_BN ? D : 1];

  int tid = threadIdx.x;
  int w = tid >> 6;               // wave = node tile 0..7
  int l = tid & 63;
  int base = blockIdx.x * NPB;
  int q8 = l & 7;                 // gather lane: features 8*q8..8*q8+7
  int s0 = w * 16 + (l >> 3);     // pass-0 slot (pass-1 = s0+8)
  int n0 = base + s0, n1 = n0 + 8;
  int lg = l >> 4, ln = l & 15;   // MFMA lane coords
  int nodeB = base + w * 16 + ln; // Phase-B node column

  // ---- t0: early global issue (no LDS dependency) ----
  int a0 = min(n0, N - 1), a1 = min(n1, N - 1);
  const int4* cp0 = (const int4*)(col + (size_t)a0 * SLOT);
  const int4* cp1 = (const int4*)(col + (size_t)a1 * SLOT);
  int4 cA0 = cp0[0], cB0 = cp0[1], cC0 = cp0[2], cD0 = cp0[3];
  int4 cA1 = cp1[0], cB1 = cp1[1], cC1 = cp1[2], cD1 = cp1[3];
  int d0 = deg[a0], d1 = deg[a1];       // only gates FOLD scale + rare tail
  HF4 self0, self1;
  self0.f4 = feat4[(size_t)min(n0, N) * 8 + q8];
  self1.f4 = feat4[(size_t)min(n1, N) * 8 + q8];
  int blB = 0, g_lo = 0, g_hi = 0;
  if (EPI == 2) {                        // prefetch pool metadata
    blB = batch[min(nodeB, N - 1)];
    g_lo = batch[min(base + w * 16, N - 1)];
    g_hi = batch[min(base + w * 16 + 15, N - 1)];
  }
  HF4 u0[16];
  load16(feat4, N, q8, cA0, cB0, cC0, cD0, u0);   // pass-0 gathers in flight

  // ---- t1: stage weights into MFMA fragment order (fp16) ----
  {
    constexpr int WA_SLOTS = MID * 16;   // half4 slots (stage1 A = Wa^T, K=64)
    constexpr int WB_SLOTS = MID * 16;   // half4 slots (stage2 A = Wb^T, K=MID)
    for (int g = tid; g < WA_SLOTS + WB_SLOTS; g += 512) {
      half4_t v;
      if (g < WA_SLOTS) {
        int ll = g & 63, kt = (g >> 6) & 3, ct = g >> 8;
        int k0 = kt * 16 + ((ll >> 4) << 2);
        int c = ct * 16 + (ll & 15);
#pragma unroll
        for (int i = 0; i < 4; i++) v[i] = (_Float16)Wa[(k0 + i) * MID + c];
        *(half4_t*)&s_wa[g * 4] = v;
      } else {
        int g2 = g - WA_SLOTS;
        int ll = g2 & 63;
        int kt = (g2 >> 6) & (CT - 1);
        int ot = g2 >> (6 + (CT == 4 ? 2 : 1));
        int k0 = kt * 16 + ((ll >> 4) << 2);
        int o = ot * 16 + (ll & 15);
#pragma unroll
        for (int i = 0; i < 4; i++) v[i] = (_Float16)Wb[(k0 + i) * D + o];
        *(half4_t*)&s_wb[g2 * 4] = v;
      }
    }
  }
  if (tid < MID) s_ba[tid] = ba[tid];
  if (tid < D) s_bb[tid] = bb[tid];
  if (FOLD_BN && tid < D) {
    float s = 0.f, q = 0.f;
#pragma unroll
    for (int b = 0; b < NBANK; b++) {    // layer-1 stats are banked
      s += bn_sum[b * D + tid];
      q += bn_sq[b * D + tid];
    }
    float mean = s * invN;
    float var = q * invN - mean * mean;
    float av = bn_gamma[tid] * rsqrtf(var + 1e-5f);
    s_bna[tid] = av;
    s_bnb[tid] = bn_beta[tid] - mean * av;
  }
  __syncthreads();   // the ONLY block-wide barrier

  // ---- t2: accumulate + LDS write (wave-local rows) ----
  {
    float2 acc[4];
#pragma unroll
    for (int c = 0; c < 4; c++) acc[c] = __half22float2(self0.h2[c]);
    acc16(u0, acc);
    if (__any(d0 > 16)) {                // ~1e-3/wave; pads gather zero row
      HF4 t[16];
      load16(feat4, N, q8, cp0[4], cp0[5], cp0[6], cp0[7], t);
      acc16(t, acc);
    }
    if (FOLD_BN) {
      float dp = (float)(min(d0, SLOT) + 1);
      int c0 = q8 * 8;
#pragma unroll
      for (int c = 0; c < 4; c++) {
        float2 a2 = *(const float2*)&s_bna[c0 + 2 * c];
        float2 b2 = *(const float2*)&s_bnb[c0 + 2 * c];
        acc[c] = f2fma(a2, acc[c], make_float2(dp * b2.x, dp * b2.y));
      }
    }
    HF4 o;
#pragma unroll
    for (int c = 0; c < 4; c++) o.h2[c] = __floats2half2_rn(acc[c].x, acc[c].y);
    *(float4*)&s_h[s0 * INH + q8 * 8] = o.f4;

    // pass 1 (indices/self prefetched at t0)
    HF4 u1[16];
    load16(feat4, N, q8, cA1, cB1, cC1, cD1, u1);
#pragma unroll
    for (int c = 0; c < 4; c++) acc[c] = __half22float2(self1.h2[c]);
    acc16(u1, acc);
    if (__any(d1 > 16)) {
      HF4 t[16];
      load16(feat4, N, q8, cp1[4], cp1[5], cp1[6], cp1[7], t);
      acc16(t, acc);
    }
    if (FOLD_BN) {
      float dp = (float)(min(d1, SLOT) + 1);
      int c0 = q8 * 8;
#pragma unroll
      for (int c = 0; c < 4; c++) {
        float2 a2 = *(const float2*)&s_bna[c0 + 2 * c];
        float2 b2 = *(const float2*)&s_bnb[c0 + 2 * c];
        acc[c] = f2fma(a2, acc[c], make_float2(dp * b2.x, dp * b2.y));
      }
    }
#pragma unroll
    for (int c = 0; c < 4; c++) o.h2[c] = __floats2half2_rn(acc[c].x, acc[c].y);
    *(float4*)&s_h[(s0 + 8) * INH + q8 * 8] = o.f4;
  }

  // Wave-local LDS handoff: this wave's writes -> this wave's reads.
  asm volatile("s_waitcnt lgkmcnt(0)" ::: "memory");
  __builtin_amdgcn_sched_barrier(0);

  // ---- t3: MFMA MLP, one 16-node column tile per wave ----
  half4_t hb[4];
#pragma unroll
  for (int kt = 0; kt < 4; kt++)
    hb[kt] = *(const half4_t*)&s_h[(w * 16 + ln) * INH + kt * 16 + lg * 4];

  float4_t c1[CT];
#pragma unroll
  for (int ct = 0; ct < CT; ct++) {
    c1[ct] = *(const float4_t*)&s_ba[ct * 16 + lg * 4];
#pragma unroll
    for (int kt = 0; kt < 4; kt++) {
      half4_t a = *(const half4_t*)&s_wa[((ct * 4 + kt) * 64 + l) * 4];
      c1[ct] = __builtin_amdgcn_mfma_f32_16x16x16f16(a, hb[kt], c1[ct], 0, 0, 0);
    }
  }
  half4_t mb[CT];
#pragma unroll
  for (int ct = 0; ct < CT; ct++) {
#pragma unroll
    for (int r = 0; r < 4; r++) mb[ct][r] = (_Float16)fmaxf(c1[ct][r], 0.f);
  }
  float4_t o4[4];
#pragma unroll
  for (int ot = 0; ot < 4; ot++) {
    o4[ot] = *(const float4_t*)&s_bb[ot * 16 + lg * 4];
#pragma unroll
    for (int kt = 0; kt < CT; kt++) {
      half4_t a = *(const half4_t*)&s_wb[((ot * CT + kt) * 64 + l) * 4];
      o4[ot] = __builtin_amdgcn_mfma_f32_16x16x16f16(a, mb[kt], o4[ot], 0, 0, 0);
    }
#pragma unroll
    for (int r = 0; r < 4; r++) o4[ot][r] = fmaxf(o4[ot][r], 0.f);
  }

  // ---- t4: per-wave epilogues (shfl reduce + banked atomics, no barriers) ---
  int bank = ((blockIdx.x & 1) << 3) | w;

  if (EPI == 1) {
    bool val = nodeB < N;
    if (val) {
#pragma unroll
      for (int ot = 0; ot < 4; ot++) {
        HF2 u;
        u.h2[0] = __floats2half2_rn(o4[ot][0], o4[ot][1]);
        u.h2[1] = __floats2half2_rn(o4[ot][2], o4[ot][3]);
        out2[(size_t)nodeB * 16 + ot * 4 + lg] = u.f2;
      }
    }
    float vm = val ? 1.f : 0.f;
#pragma unroll
    for (int ot = 0; ot < 4; ot++) {
      float4_t s, q;
#pragma unroll
      for (int r = 0; r < 4; r++) {
        float xx = vm * o4[ot][r];
        s[r] = xx; q[r] = xx * o4[ot][r];
      }
#pragma unroll
      for (int m = 1; m < 16; m <<= 1) {
#pragma unroll
        for (int r = 0; r < 4; r++) {
          s[r] += __shfl_xor(s[r], m);
          q[r] += __shfl_xor(q[r], m);
        }
      }
      if (ln == 0) {
        int cb = ot * 16 + lg * 4;
#pragma unroll
        for (int r = 0; r < 4; r++) {
          atomicAdd(&st_sum[bank * D + cb + r], s[r]);
          atomicAdd(&st_sq[bank * D + cb + r], q[r]);
        }
      }
    }
  }

  if (EPI == 2) {
    bool val = nodeB < N;
    float vm = val ? 1.f : 0.f;
    float wlo = (val && blB == g_lo) ? 1.f : 0.f;
    unsigned long long mlo = __ballot(lg == 0 && val && blB == g_lo);
    unsigned long long mhi = __ballot(lg == 0 && val && blB != g_lo);
    if (l == 0) {
      atomicAdd(&cnt[g_lo], (float)__popcll(mlo));
      if (g_hi != g_lo) atomicAdd(&cnt[g_hi], (float)__popcll(mhi));
    }
#pragma unroll
    for (int ot = 0; ot < 4; ot++) {
      float4_t sl, st, sq;
#pragma unroll
      for (int r = 0; r < 4; r++) {
        float xx = vm * o4[ot][r];
        sl[r] = wlo * o4[ot][r];
        st[r] = xx;
        sq[r] = xx * o4[ot][r];
      }
#pragma unroll
      for (int m = 1; m < 16; m <<= 1) {
#pragma unroll
        for (int r = 0; r < 4; r++) {
          sl[r] += __shfl_xor(sl[r], m);
          st[r] += __shfl_xor(st[r], m);
          sq[r] += __shfl_xor(sq[r], m);
        }
      }
      if (ln == 0) {
        int cb = ot * 16 + lg * 4;
#pragma unroll
        for (int r = 0; r < 4; r++)
          atomicAdd(&st_sum[g_lo * D + cb + r], sl[r]);
        if (g_hi != g_lo) {
#pragma unroll
          for (int r = 0; r < 4; r++)
            atomicAdd(&st_sum[g_hi * D + cb + r], st[r] - sl[r]);
        }
#pragma unroll
        for (int r = 0; r < 4; r++)
          atomicAdd(&st_sq[bank * D + cb + r], sq[r]);
      }
    }
  }
}

// ---------------------------------------------------------------------------
// Final: BN2 coeffs from (Σ_g pool, banked sq) + fused affine + mean divide.
// ---------------------------------------------------------------------------
__global__ void final_kernel(const float* __restrict__ pool,
                             const float* __restrict__ cnt,
                             const float* __restrict__ sq,
                             const float* __restrict__ gamma,
                             const float* __restrict__ beta,
                             float invN, float* __restrict__ out) {
  int c = threadIdx.x;   // 64 threads
  float s = 0.f;
#pragma unroll
  for (int g = 0; g < NG; g++) s += pool[g * D + c];
  float q = 0.f;
#pragma unroll
  for (int b = 0; b < NBANK; b++) q += sq[b * D + c];
  float mean = s * invN;
  float var = q * invN - mean * mean;
  float a = gamma[c] * rsqrtf(var + 1e-5f);
  float b = beta[c] - mean * a;
#pragma unroll
  for (int g = 0; g < NG; g++) {
    float n = cnt[g];
    out[g * D + c] = (a * pool[g * D + c] + n * b) / fmaxf(n, 1.f);
  }
}

extern "C" void kernel_launch(void* const* d_in, const int* in_sizes, int n_in,
                              void* d_out, int out_size, void* d_ws, size_t ws_size,
                              hipStream_t stream) {
  const float* x   = (const float*)d_in[0];
  const int* ei    = (const int*)d_in[1];
  const int* batch = (const int*)d_in[2];
  const float* W1a = (const float*)d_in[5];
  const float* b1a = (const float*)d_in[6];
  const float* W1b = (const float*)d_in[7];
  const float* b1b = (const float*)d_in[8];
  const float* g1  = (const float*)d_in[9];
  const float* be1 = (const float*)d_in[10];
  const float* W2a = (const float*)d_in[11];
  const float* b2a = (const float*)d_in[12];
  const float* W2b = (const float*)d_in[13];
  const float* b2b = (const float*)d_in[14];
  const float* g2  = (const float*)d_in[15];
  const float* be2 = (const float*)d_in[16];

  int N = in_sizes[0] / D;        // 100000
  int E = in_sizes[1] / 2;        // 1600000
  int per = E / NG;               // 100000
  int tmul = N / NG;              // 6250
  float invN = 1.f / (float)N;

  float* ws = (float*)d_ws;
  size_t ndh = (size_t)(N + 1) * D / 2;  // fp16 table size in floats (N+1 rows)
  float* h1h = ws;                       // h1 (pre-BN) fp16 table, N+1 rows
  float* xh  = ws + ndh;                 // x fp16 table, N+1 rows
  int*   col = (int*)(ws + 2 * ndh);     // CSR src lists (N*SLOT ints)
  float* stats = ws + 2 * ndh + (size_t)N * SLOT;
  float* sum1 = stats;                   // NBANK*64 (banked)
  float* sq1  = stats + NBANK * D;       // NBANK*64 (banked)
  float* pool = stats + 2 * NBANK * D;   // 16*64 (direct per-graph)
  float* cnt  = pool + NG * D;           // 16
  float* sq2  = cnt + NG;                // NBANK*64 (banked)
  int*   fill = (int*)(sq2 + NBANK * D); // N ints (degree counts)
  size_t nstat = 3 * NBANK * D + NG * D + NG;

  // Zero stats + fill; fill col with 0x7F7F7F7F (>= N -> min-clamps to pad row).
  hipMemsetAsync(stats, 0, (nstat + N) * sizeof(float), stream);
  hipMemsetAsync(col, 0x7F, (size_t)N * SLOT * sizeof(int), stream);

  // Fused prep: x->fp16 + pad-row zero + CSR build (n4 == E here).
  int n4 = N * D / 4;
  int pgrid = (max(n4, E) + 255) / 256;
  prep_kernel<<<pgrid, 256, 0, stream>>>(
      x, (float2*)xh, n4,
      (float4*)(xh + (size_t)N * D / 2),
      (float4*)(h1h + (size_t)N * D / 2),
      ei, fill, col, E, per, tmul);

  int fblocks = (N + NPB - 1) / NPB;   // 782

  // Layer 1: gather(xh) + MFMA MLP1 -> h1h (fp16, pre-BN) + banked BN1 stats
  fused_layer_kernel<32, false, 1><<<fblocks, 512, 0, stream>>>(
      (const float4*)xh, col, fill, nullptr, nullptr, nullptr, nullptr, invN,
      W1a, b1a, W1b, b1b, (float2*)h1h, nullptr, sum1, sq1, nullptr, N);

  // Layer 2: BN1 folded into gather input; pool + sumsq epilogue (no h2)
  fused_layer_kernel<64, true, 2><<<fblocks, 512, 0, stream>>>(
      (const float4*)h1h, col, fill, sum1, sq1, g1, be1, invN,
      W2a, b2a, W2b, b2b, nullptr, batch, pool, sq2, cnt, N);

  // BN2 coeffs + affine + mean.
  final_kernel<<<1, 64, 0, stream>>>(pool, cnt, sq2, g2, be2, invN, (float*)d_out);
}

// Round 3
// 221.065 us; speedup vs baseline: 1.4774x; 1.4774x over previous
//
#include <hip/hip_runtime.h>
#include <hip/hip_fp16.h>

#define NG 16     // num_graphs (fixed by problem)
#define D 64      // feature width at every aggregation point
#define SLOT 32   // CSR slots/node; max in-degree ~Poisson(8.5), P(>=32)~1e-11
#define NPB 128   // nodes per block (512 threads, 8 waves = 8 node-tiles of 16)
#define INH 72    // s_h row stride in halfs (64 + 8 pad: 8B-aligned, bank-balanced)

// fp16 feature rows: 64 halfs = 128 B = 8 float4s. 8 lanes/node, 16 B/lane.
// Tables have N+1 rows; row N is all-zero (gather pad target).
// col[] is memset to 0x7F7F7F7F each launch: pad slots min-clamp to row N,
// so the gather needs NO deg-dependent index selects (shorter dep chain,
// ~32 fewer VALU/round, deg off the critical path).
// VGPR budget note: LDS 36 KB -> 4 blocks/CU -> 8 waves/SIMD -> VGPR MUST
// stay <= 64 (round-2's 80-VGPR variant dropped to 3 blocks/CU and convoyed:
// 135 us). Keep per-thread liveness lean.
union HF4 { float4 f4; __half2 h2[4]; };
union HF2 { float2 f2; __half2 h2[2]; };

typedef _Float16 half4_t __attribute__((ext_vector_type(4)));
typedef float float4_t __attribute__((ext_vector_type(4)));

__device__ __forceinline__ float2 f2fma(float2 a, float2 b, float2 c) {
  return make_float2(fmaf(a.x, b.x, c.x), fmaf(a.y, b.y, c.y));
}
__device__ __forceinline__ float2 f2add(float2 a, float2 b) {
  return make_float2(a.x + b.x, a.y + b.y);
}

// Issue 16 min-clamped feature gathers (pad slots -> zero row N).
__device__ __forceinline__ void load16(const float4* __restrict__ feat4, int N,
                                       int q8, int4 a, int4 b, int4 c, int4 d,
                                       HF4* u) {
  int ix[16] = {a.x, a.y, a.z, a.w, b.x, b.y, b.z, b.w,
                c.x, c.y, c.z, c.w, d.x, d.y, d.z, d.w};
#pragma unroll
  for (int i = 0; i < 16; i++)
    u[i].f4 = feat4[(size_t)min(ix[i], N) * 8 + q8];
}
__device__ __forceinline__ void acc16(const HF4* u, float2* acc) {
#pragma unroll
  for (int i = 0; i < 16; i++) {
#pragma unroll
    for (int c = 0; c < 4; c++)
      acc[c] = f2add(acc[c], __half22float2(u[i].h2[c]));
  }
}

// ---------------------------------------------------------------------------
// Fused prep: x->fp16 convert (t < n4) + CSR build (t < E) + pad-row zeroing.
// ---------------------------------------------------------------------------
__global__ void prep_kernel(const float* __restrict__ x,
                            float2* __restrict__ xh, int n4,
                            float4* __restrict__ xz, float4* __restrict__ hz,
                            const int* __restrict__ ei,
                            int* __restrict__ fill, int* __restrict__ col,
                            int E, int per, int tmul) {
  int t = blockIdx.x * 256 + threadIdx.x;
  if (blockIdx.x == 0 && threadIdx.x < 16) {
    float4 z = make_float4(0.f, 0.f, 0.f, 0.f);
    if (threadIdx.x < 8) xz[threadIdx.x] = z;
    else hz[threadIdx.x - 8] = z;
  }
  if (t < n4) {
    float4 v = ((const float4*)x)[t];
    HF2 u;
    u.h2[0] = __floats2half2_rn(v.x, v.y);
    u.h2[1] = __floats2half2_rn(v.z, v.w);
    xh[t] = u.f2;
  }
  if (t < E) {
    int src = ei[t];
    int dst = ei[E + t];
    int thr = (t / per) * tmul;       // compiler magic-div
    if (src >= thr && dst >= thr) {
      int k = atomicAdd(&fill[dst], 1);
      if (k < SLOT) col[dst * SLOT + k] = src;
    }
  }
}

// ---------------------------------------------------------------------------
// Fused layer: fp16 gather + (optional BN fold) + MFMA MLP + epilogue.
// Round-1 schedule (proven 57 us): stage weights | barrier | interleaved
// gather loop (issue/consume pipelined by the compiler) | barrier | MFMA |
// per-wave shfl reduce + cross-wave LDS sum + atomics.
//   stage1: C1 = Wa^T (MIDx64) @ h^T (64x64nodes)  -> C1[c][node]
//   stage2: out^T = Wb^T (64xMID) @ mid^T           -> out[node][o]
// stage1's C/D fragment layout IS stage2's B-fragment -> relu + fp16-pack
// entirely in registers. Each wave owns one 16-node column tile.
// ---------------------------------------------------------------------------
template <int MID, bool FOLD_BN, int EPI>
__global__ __launch_bounds__(512, 2) void fused_layer_kernel(
    const float4* __restrict__ feat4,   // fp16 table, 8 float4/row, N+1 rows
    const int* __restrict__ col, const int* __restrict__ deg,
    const float* __restrict__ bn_sum, const float* __restrict__ bn_sq,
    const float* __restrict__ bn_gamma, const float* __restrict__ bn_beta,
    float invN,
    const float* __restrict__ Wa, const float* __restrict__ ba,
    const float* __restrict__ Wb, const float* __restrict__ bb,
    float2* __restrict__ out2,          // EPI==1 only (fp16 rows)
    const int* __restrict__ batch,      // EPI==2 only
    float* __restrict__ st_sum,         // EPI==1: sum[64]; EPI==2: pool[NG*64]
    float* __restrict__ st_sq,          // sumsq[64]
    float* __restrict__ cnt,            // EPI==2 only
    int N) {
  constexpr int CT = MID / 16;          // stage-1 c-tiles == stage-2 k-tiles

  __shared__ __align__(16) __half s_h[NPB * INH];     // 18432 B, fp16 gather out
  __shared__ __align__(16) __half s_wa[MID * 64];     // Wa^T fragment order
  __shared__ __align__(16) __half s_wb[64 * MID];     // Wb^T fragment order
  __shared__ __align__(16) float s_ba[MID];
  __shared__ __align__(16) float s_bb[D];
  __shared__ float s_bna[FOLD_BN ? D : 1];
  __shared__ float s_bnb[FOLD_BN ? D : 1];
  __shared__ int s_cnt[2];

  int tid = threadIdx.x;
  int base = blockIdx.x * NPB;

  // ---- Stage weights into MFMA fragment order (fp16), coalesced-ish ----
  {
    constexpr int WA_SLOTS = MID * 16;   // half4 slots (stage1 A = Wa^T, K=64)
    constexpr int WB_SLOTS = MID * 16;   // half4 slots (stage2 A = Wb^T, K=MID)
    for (int g = tid; g < WA_SLOTS + WB_SLOTS; g += 512) {
      half4_t v;
      if (g < WA_SLOTS) {
        int l = g & 63, kt = (g >> 6) & 3, ct = g >> 8;
        int k0 = kt * 16 + ((l >> 4) << 2);
        int c = ct * 16 + (l & 15);
#pragma unroll
        for (int i = 0; i < 4; i++) v[i] = (_Float16)Wa[(k0 + i) * MID + c];
        *(half4_t*)&s_wa[g * 4] = v;
      } else {
        int g2 = g - WA_SLOTS;
        int l = g2 & 63;
        int kt = (g2 >> 6) & (CT - 1);
        int ot = g2 >> (6 + (CT == 4 ? 2 : 1));
        int k0 = kt * 16 + ((l >> 4) << 2);
        int o = ot * 16 + (l & 15);
#pragma unroll
        for (int i = 0; i < 4; i++) v[i] = (_Float16)Wb[(k0 + i) * D + o];
        *(half4_t*)&s_wb[g2 * 4] = v;
      }
    }
  }
  if (tid < MID) s_ba[tid] = ba[tid];
  if (tid < D) s_bb[tid] = bb[tid];
  if (FOLD_BN && tid < D) {
    float mean = bn_sum[tid] * invN;
    float var = bn_sq[tid] * invN - mean * mean;
    float av = bn_gamma[tid] * rsqrtf(var + 1e-5f);
    s_bna[tid] = av;
    s_bnb[tid] = bn_beta[tid] - mean * av;
  }
  if (EPI == 2 && tid < 2) s_cnt[tid] = 0;
  __syncthreads();

  // ---- Phase A: 8 lanes/node fp16 gather, 2 sequential slots/thread ----
  {
    int q8 = tid & 7;             // lane covers features 8*q8 .. 8*q8+7
#pragma unroll
    for (int s0 = 0; s0 < 2; s0++) {
      int slot = (tid >> 3) + 64 * s0;
      int node = base + slot;
      float2 acc[4];              // 8 features as 4 packed float2 (fp32 accum)
      if (node < N) {
        int d = min(deg[node], SLOT);
        const int4* cp = (const int4*)(col + (size_t)node * SLOT);
        {
          HF4 s; s.f4 = feat4[(size_t)node * 8 + q8];   // self term
#pragma unroll
          for (int i = 0; i < 4; i++) acc[i] = __half22float2(s.h2[i]);
        }
        // first 16 slots: unconditional, pad slots min-clamp to zero row N
        HF4 u[16];
        load16(feat4, N, q8, cp[0], cp[1], cp[2], cp[3], u);
        acc16(u, acc);
        if (__any(d > 16)) {      // rare tail (P~5%/wave); pads gather zero row
          load16(feat4, N, q8, cp[4], cp[5], cp[6], cp[7], u);
          acc16(u, acc);
        }
        if (FOLD_BN) {
          float dp = (float)(d + 1);
          int c0 = q8 * 8;
#pragma unroll
          for (int c = 0; c < 4; c++) {
            float2 a2 = *(const float2*)&s_bna[c0 + 2 * c];
            float2 b2 = *(const float2*)&s_bnb[c0 + 2 * c];
            acc[c] = f2fma(a2, acc[c], make_float2(dp * b2.x, dp * b2.y));
          }
        }
      } else {
#pragma unroll
        for (int i = 0; i < 4; i++) acc[i] = make_float2(0.f, 0.f);
      }
      HF4 o;
#pragma unroll
      for (int c = 0; c < 4; c++)
        o.h2[c] = __floats2half2_rn(acc[c].x, acc[c].y);
      *(float4*)&s_h[slot * INH + q8 * 8] = o.f4;
    }
  }
  __syncthreads();

  // ---- Phase B: MFMA MLP, one 16-node column tile per wave ----
  int w = tid >> 6;               // wave = node tile 0..7
  int l = tid & 63;
  int lg = l >> 4;                // 0..3
  int ln = l & 15;                // node within tile
  int nodeB = base + w * 16 + ln; // this lane's node column

  // B-fragments of h^T: lane l holds h[node][kt*16 + 4*lg .. +3]
  half4_t hb[4];
#pragma unroll
  for (int kt = 0; kt < 4; kt++)
    hb[kt] = *(const half4_t*)&s_h[(w * 16 + ln) * INH + kt * 16 + lg * 4];

  // stage 1: C1[c][node] = Wa^T @ h^T + ba
  float4_t c1[CT];
#pragma unroll
  for (int ct = 0; ct < CT; ct++) {
    c1[ct] = *(const float4_t*)&s_ba[ct * 16 + lg * 4];   // exact fp32 bias
#pragma unroll
    for (int kt = 0; kt < 4; kt++) {
      half4_t a = *(const half4_t*)&s_wa[((ct * 4 + kt) * 64 + l) * 4];
      c1[ct] = __builtin_amdgcn_mfma_f32_16x16x16f16(a, hb[kt], c1[ct], 0, 0, 0);
    }
  }
  // relu + fp16: stage1 C/D frag == stage2 B frag (same lane, r==i)
  half4_t mb[CT];
#pragma unroll
  for (int ct = 0; ct < CT; ct++) {
#pragma unroll
    for (int r = 0; r < 4; r++) mb[ct][r] = (_Float16)fmaxf(c1[ct][r], 0.f);
  }
  // stage 2: out[node][o] = (Wb^T @ mid^T)^T + bb, then relu
  float4_t o4[4];
#pragma unroll
  for (int ot = 0; ot < 4; ot++) {
    o4[ot] = *(const float4_t*)&s_bb[ot * 16 + lg * 4];
#pragma unroll
    for (int kt = 0; kt < CT; kt++) {
      half4_t a = *(const half4_t*)&s_wb[((ot * CT + kt) * 64 + l) * 4];
      o4[ot] = __builtin_amdgcn_mfma_f32_16x16x16f16(a, mb[kt], o4[ot], 0, 0, 0);
    }
#pragma unroll
    for (int r = 0; r < 4; r++) o4[ot][r] = fmaxf(o4[ot][r], 0.f);
  }

  // Reduction scratch: each wave reuses ITS OWN s_h region (2304 B = 576 f32;
  // hb regs already loaded; barrier below orders reuse).
  float* red = (float*)s_h;

  if (EPI == 1) {
    // ---- store h1 fp16 + BN-stats (sum, sumsq over valid nodes) ----
    bool val = nodeB < N;
    if (val) {
#pragma unroll
      for (int ot = 0; ot < 4; ot++) {
        HF2 u;
        u.h2[0] = __floats2half2_rn(o4[ot][0], o4[ot][1]);
        u.h2[1] = __floats2half2_rn(o4[ot][2], o4[ot][3]);
        out2[(size_t)nodeB * 16 + ot * 4 + lg] = u.f2;
      }
    }
    float vm = val ? 1.f : 0.f;
#pragma unroll
    for (int ot = 0; ot < 4; ot++) {
      float4_t s, q;
#pragma unroll
      for (int r = 0; r < 4; r++) {
        float x = vm * o4[ot][r];
        s[r] = x; q[r] = x * o4[ot][r];
      }
#pragma unroll
      for (int m = 1; m < 16; m <<= 1) {
#pragma unroll
        for (int r = 0; r < 4; r++) {
          s[r] += __shfl_xor(s[r], m);
          q[r] += __shfl_xor(q[r], m);
        }
      }
      if (ln == 0) {
        *(float4_t*)&red[w * 576 + ot * 16 + lg * 4] = s;
        *(float4_t*)&red[w * 576 + 64 + ot * 16 + lg * 4] = q;
      }
    }
    __syncthreads();
    if (tid < D) {
      float s = 0.f, q = 0.f;
#pragma unroll
      for (int ww = 0; ww < 8; ww++) {
        s += red[ww * 576 + tid];
        q += red[ww * 576 + 64 + tid];
      }
      atomicAdd(&st_sum[tid], s);
      atomicAdd(&st_sq[tid], q);
    }
  }

  if (EPI == 2) {
    // ---- Pool epilogue: <=2 graphs per 128-node block (sorted batch) ----
    bool val = nodeB < N;
    int bl = val ? batch[nodeB] : -1;
    int g_lo = batch[base];
    int g_hi = batch[min(base + NPB - 1, N - 1)];
    float vm = val ? 1.f : 0.f;
    float wlo = (bl == g_lo) ? 1.f : 0.f;
    // counts: one lane-group (lg==0) per node so each node counts once
    unsigned long long mlo = __ballot(lg == 0 && bl == g_lo);
    unsigned long long mhi = __ballot(lg == 0 && val && bl != g_lo);
    if (l == 0) {
      atomicAdd(&s_cnt[0], (int)__popcll(mlo));
      atomicAdd(&s_cnt[1], (int)__popcll(mhi));
    }
#pragma unroll
    for (int ot = 0; ot < 4; ot++) {
      float4_t sl, st, sq;
#pragma unroll
      for (int r = 0; r < 4; r++) {
        float x = vm * o4[ot][r];
        sl[r] = wlo * x;          // sum over g_lo nodes
        st[r] = x;                // sum over all valid (hi = tot - lo)
        sq[r] = x * o4[ot][r];    // sumsq over all valid
      }
#pragma unroll
      for (int m = 1; m < 16; m <<= 1) {
#pragma unroll
        for (int r = 0; r < 4; r++) {
          sl[r] += __shfl_xor(sl[r], m);
          st[r] += __shfl_xor(st[r], m);
          sq[r] += __shfl_xor(sq[r], m);
        }
      }
      if (ln == 0) {
        *(float4_t*)&red[w * 576 + ot * 16 + lg * 4] = sl;
        float4_t sh;
#pragma unroll
        for (int r = 0; r < 4; r++) sh[r] = st[r] - sl[r];
        *(float4_t*)&red[w * 576 + 64 + ot * 16 + lg * 4] = sh;
        *(float4_t*)&red[w * 576 + 128 + ot * 16 + lg * 4] = sq;
      }
    }
    __syncthreads();
    if (tid < D) {
      float sl = 0.f, sh = 0.f, sq = 0.f;
#pragma unroll
      for (int ww = 0; ww < 8; ww++) {
        sl += red[ww * 576 + tid];
        sh += red[ww * 576 + 64 + tid];
        sq += red[ww * 576 + 128 + tid];
      }
      atomicAdd(&st_sum[g_lo * D + tid], sl);
      if (g_hi != g_lo) atomicAdd(&st_sum[g_hi * D + tid], sh);
      atomicAdd(&st_sq[tid], sq);
    }
    if (tid == 0) {
      atomicAdd(&cnt[g_lo], (float)s_cnt[0]);
      if (g_hi != g_lo) atomicAdd(&cnt[g_hi], (float)s_cnt[1]);
    }
  }
}

// ---------------------------------------------------------------------------
// Final: BN2 coeffs from (Σ_g pool, sq) + fused affine + mean divide.
// ---------------------------------------------------------------------------
__global__ void final_kernel(const float* __restrict__ pool,
                             const float* __restrict__ cnt,
                             const float* __restrict__ sq,
                             const float* __restrict__ gamma,
                             const float* __restrict__ beta,
                             float invN, float* __restrict__ out) {
  int c = threadIdx.x;   // 64 threads
  float s = 0.f;
#pragma unroll
  for (int g = 0; g < NG; g++) s += pool[g * D + c];
  float mean = s * invN;
  float var = sq[c] * invN - mean * mean;
  float a = gamma[c] * rsqrtf(var + 1e-5f);
  float b = beta[c] - mean * a;
#pragma unroll
  for (int g = 0; g < NG; g++) {
    float n = cnt[g];
    out[g * D + c] = (a * pool[g * D + c] + n * b) / fmaxf(n, 1.f);
  }
}

extern "C" void kernel_launch(void* const* d_in, const int* in_sizes, int n_in,
                              void* d_out, int out_size, void* d_ws, size_t ws_size,
                              hipStream_t stream) {
  const float* x   = (const float*)d_in[0];
  const int* ei    = (const int*)d_in[1];
  const int* batch = (const int*)d_in[2];
  const float* W1a = (const float*)d_in[5];
  const float* b1a = (const float*)d_in[6];
  const float* W1b = (const float*)d_in[7];
  const float* b1b = (const float*)d_in[8];
  const float* g1  = (const float*)d_in[9];
  const float* be1 = (const float*)d_in[10];
  const float* W2a = (const float*)d_in[11];
  const float* b2a = (const float*)d_in[12];
  const float* W2b = (const float*)d_in[13];
  const float* b2b = (const float*)d_in[14];
  const float* g2  = (const float*)d_in[15];
  const float* be2 = (const float*)d_in[16];

  int N = in_sizes[0] / D;        // 100000
  int E = in_sizes[1] / 2;        // 1600000
  int per = E / NG;               // 100000
  int tmul = N / NG;              // 6250
  float invN = 1.f / (float)N;

  float* ws = (float*)d_ws;
  size_t ndh = (size_t)(N + 1) * D / 2;  // fp16 table size in floats (N+1 rows)
  float* h1h = ws;                       // h1 (pre-BN) fp16 table, N+1 rows
  float* xh  = ws + ndh;                 // x fp16 table, N+1 rows
  int*   col = (int*)(ws + 2 * ndh);     // CSR src lists (N*SLOT ints)
  float* stats = ws + 2 * ndh + (size_t)N * SLOT;
  float* sum1 = stats;                   // 64
  float* sq1  = stats + 64;              // 64
  float* pool = stats + 128;             // 16*64
  float* cnt  = stats + 128 + NG * D;    // 16
  float* sq2  = stats + 144 + NG * D;    // 64
  int*   fill = (int*)(stats + 208 + NG * D);  // N ints (degree counts)

  // Zero stats + fill; fill col with 0x7F7F7F7F (>= N -> min-clamps to pad row).
  hipMemsetAsync(stats, 0, (208 + NG * D + N) * sizeof(float), stream);
  hipMemsetAsync(col, 0x7F, (size_t)N * SLOT * sizeof(int), stream);

  // Fused prep: x->fp16 + pad-row zero + CSR build (n4 == E here).
  int n4 = N * D / 4;
  int pgrid = (max(n4, E) + 255) / 256;
  prep_kernel<<<pgrid, 256, 0, stream>>>(
      x, (float2*)xh, n4,
      (float4*)(xh + (size_t)N * D / 2),
      (float4*)(h1h + (size_t)N * D / 2),
      ei, fill, col, E, per, tmul);

  int fblocks = (N + NPB - 1) / NPB;   // 782

  // Layer 1: gather(xh) + MFMA MLP1 -> h1h (fp16, pre-BN) + BN1-stats epilogue
  fused_layer_kernel<32, false, 1><<<fblocks, 512, 0, stream>>>(
      (const float4*)xh, col, fill, nullptr, nullptr, nullptr, nullptr, invN,
      W1a, b1a, W1b, b1b, (float2*)h1h, nullptr, sum1, sq1, nullptr, N);

  // Layer 2: BN1 folded into gather input; pool + sumsq epilogue (no h2)
  fused_layer_kernel<64, true, 2><<<fblocks, 512, 0, stream>>>(
      (const float4*)h1h, col, fill, sum1, sq1, g1, be1, invN,
      W2a, b2a, W2b, b2b, nullptr, batch, pool, sq2, cnt, N);

  // BN2 coeffs + affine + mean.
  final_kernel<<<1, 64, 0, stream>>>(pool, cnt, sq2, g2, be2, invN, (float*)d_out);
}